// Round 2
// baseline (577.649 us; speedup 1.0000x reference)
//
#include <hip/hip_runtime.h>
#include <hip/hip_bf16.h>
#include <math.h>

#define N_ 32
#define C_ 256
#define C4_ 64
#define L_ 6
#define T_ 64
#define V_ 25
#define VP 28          // padded V for float4 LDS tiles
#define EPS_ 1e-5f

// LAYERS flattened (joint indices per hierarchy level) + offsets
__device__ __constant__ int LIDX[45] = {
    1, 0, 20,
    0, 20, 12, 16, 2, 4, 8,
    12, 16, 2, 4, 8, 13, 17, 3, 5, 9,
    13, 17, 3, 5, 9, 14, 18, 6, 10,
    14, 18, 6, 10, 15, 19, 7, 11,
    15, 19, 7, 11, 21, 22, 23, 24};
__device__ __constant__ int LOFF[7] = {0, 3, 10, 20, 29, 37, 45};

// ---------------- kernel 0: transpose W_down and W_agg into workspace -------
__global__ __launch_bounds__(256) void k_wt(const float* __restrict__ Wd,
                                            const float* __restrict__ Wa,
                                            float* __restrict__ wtd,
                                            float* __restrict__ wat) {
  int tid = blockIdx.x * 256 + threadIdx.x;
  if (tid < C4_ * C_) {                 // W_down (64,256) -> [c][o]
    int o = tid / C_, c = tid - o * C_;
    wtd[c * C4_ + o] = Wd[tid];
  } else if (tid < 2 * C4_ * C_) {      // W_agg (256,64) -> [c][oc]
    int i = tid - C4_ * C_;
    int oc = i / C4_, c = i - oc * C4_;
    wat[c * C_ + oc] = Wa[i];
  }
}

// ---------------- kernel 1: max over T  (N,C,L,T,V) -> (N,C,L,V) ------------
__global__ __launch_bounds__(256) void k_maxT(const float* __restrict__ x,
                                              float* __restrict__ xt) {
  int idx = blockIdx.x * 256 + threadIdx.x;
  const int total = N_ * C_ * L_ * V_;
  if (idx >= total) return;
  int row = idx / V_;          // linear (n,c,l)
  int v = idx - row * V_;
  const float* p = x + (size_t)row * (T_ * V_) + v;
  float m = -INFINITY;
#pragma unroll 16
  for (int t = 0; t < T_; ++t) m = fmaxf(m, p[t * V_]);
  xt[idx] = m;
}

// ---------------- kernel 2: conv_down + BN + ReLU + joint-subset mean -------
// one block per (n,l); 128 threads; thread = (o_group 0..15) x (v_group 0..6)
__global__ __launch_bounds__(128) void k_down(
    const float* __restrict__ xt, const float* __restrict__ wtd,
    const float* __restrict__ bd, const float* __restrict__ gd,
    const float* __restrict__ bed, const float* __restrict__ md,
    const float* __restrict__ vd, float* __restrict__ s_out) {
  __shared__ float wls[64 * C4_];   // W chunk [c_local][o]  16 KB
  __shared__ float xs[64 * VP];     // x_t chunk [c_local][v] 7 KB
  __shared__ float hs[C4_ * VP];    // h [o][v]               7 KB

  int n = blockIdx.x / L_, l = blockIdx.x - n * L_;
  int t = threadIdx.x;
  int o0 = (t & 15) * 4;
  int vg = t >> 4;                  // 0..7
  bool active = vg < 7;
  int v0 = vg * 4;

  float acc[4][4] = {};

  for (int cc = 0; cc < C_; cc += 64) {
    __syncthreads();
    // stage W chunk (coalesced float4 from pre-transposed global)
    {
      const float4* src = (const float4*)(wtd + cc * C4_);
      float4* dst = (float4*)wls;
      for (int i = t; i < 64 * C4_ / 4; i += 128) dst[i] = src[i];
    }
    // stage x_t chunk with zero pad
    for (int i = t; i < 64 * VP; i += 128) {
      int c = i / VP, v = i - c * VP;
      xs[i] = (v < V_) ? xt[(((size_t)n * C_ + (cc + c)) * L_ + l) * V_ + v]
                       : 0.f;
    }
    __syncthreads();
    if (active) {
#pragma unroll 4
      for (int c = 0; c < 64; ++c) {
        float4 wv = *(const float4*)&wls[c * C4_ + o0];
        float4 xv = *(const float4*)&xs[c * VP + v0];
        acc[0][0] = fmaf(wv.x, xv.x, acc[0][0]);
        acc[0][1] = fmaf(wv.x, xv.y, acc[0][1]);
        acc[0][2] = fmaf(wv.x, xv.z, acc[0][2]);
        acc[0][3] = fmaf(wv.x, xv.w, acc[0][3]);
        acc[1][0] = fmaf(wv.y, xv.x, acc[1][0]);
        acc[1][1] = fmaf(wv.y, xv.y, acc[1][1]);
        acc[1][2] = fmaf(wv.y, xv.z, acc[1][2]);
        acc[1][3] = fmaf(wv.y, xv.w, acc[1][3]);
        acc[2][0] = fmaf(wv.z, xv.x, acc[2][0]);
        acc[2][1] = fmaf(wv.z, xv.y, acc[2][1]);
        acc[2][2] = fmaf(wv.z, xv.z, acc[2][2]);
        acc[2][3] = fmaf(wv.z, xv.w, acc[2][3]);
        acc[3][0] = fmaf(wv.w, xv.x, acc[3][0]);
        acc[3][1] = fmaf(wv.w, xv.y, acc[3][1]);
        acc[3][2] = fmaf(wv.w, xv.z, acc[3][2]);
        acc[3][3] = fmaf(wv.w, xv.w, acc[3][3]);
      }
    }
  }
  if (active) {
#pragma unroll
    for (int oj = 0; oj < 4; ++oj) {
      int o = o0 + oj;
      float sc = gd[o] * rsqrtf(vd[o] + EPS_);
      float base = bd[o] - md[o];
#pragma unroll
      for (int vj = 0; vj < 4; ++vj) {
        float hv = (acc[oj][vj] + base) * sc + bed[o];
        hs[o * VP + v0 + vj] = fmaxf(hv, 0.f);
      }
    }
  }
  __syncthreads();
  // joint-subset mean -> s[n][o][l]
  if (t < C4_) {
    float a = 0.f;
    int b0 = LOFF[l], b1 = LOFF[l + 1];
    for (int j = b0; j < b1; ++j) a += hs[t * VP + LIDX[j]];
    s_out[((size_t)n * C4_ + t) * L_ + l] = a / (float)(b1 - b0);
  }
}

// ---------------- kernel 3: EdgeConv + aggregate + sigmoid gate -------------
// one block per n; 256 threads
__global__ __launch_bounds__(256) void k_edge(
    const float* __restrict__ s_in, const float* __restrict__ We,
    const float* __restrict__ ge, const float* __restrict__ bee,
    const float* __restrict__ me, const float* __restrict__ ve,
    const float* __restrict__ wat, const float* __restrict__ ba,
    float* __restrict__ gate) {
  __shared__ float ss[C4_ * L_];     // s [c][i]
  __shared__ float P1[C4_ * L_];     // dot(W_edge[:, :64][o], s[:,j])
  __shared__ float P2[C4_ * L_];     // dot(W_edge[:, 64:][o], s[:,j])
  __shared__ float dist[L_ * L_];
  __shared__ int knn[L_ * 3];
  __shared__ float el[C4_ * L_];     // e after max over k, [c][i]

  int n = blockIdx.x;
  int t = threadIdx.x;
  // BUGFIX (round 1): C4_*L_ = 384 > 256 threads -> must grid-stride, the
  // old `if (t < 384) ss[t] = ...` left ss[256..383] uninitialized.
  for (int q = t; q < C4_ * L_; q += 256)
    ss[q] = s_in[(size_t)n * (C4_ * L_) + q];
  __syncthreads();

  if (t < 36) {
    int i = t / 6, j = t - (t / 6) * 6;
    float d = 0.f;
    for (int c = 0; c < C4_; ++c) {
      float df = ss[c * 6 + i] - ss[c * 6 + j];
      d = fmaf(df, df, d);
    }
    dist[t] = -d;   // exact 0 on diagonal, negative elsewhere
  }
  __syncthreads();
  if (t < 6) {
    unsigned used = 0;
    for (int k = 0; k < 3; ++k) {
      float best = -INFINITY;
      int bj = 0;
      for (int j = 0; j < 6; ++j) {
        if (!((used >> j) & 1u) && dist[t * 6 + j] > best) {
          best = dist[t * 6 + j];
          bj = j;
        }
      }
      used |= 1u << bj;
      knn[t * 3 + k] = bj;
    }
  }
  __syncthreads();

  for (int q = t; q < 2 * C4_ * L_; q += 256) {
    int half = q / (C4_ * L_);
    int r = q - half * (C4_ * L_);
    int o = r / 6, j = r - o * 6;
    const float* w = We + o * 128 + half * 64;
    float a = 0.f;
#pragma unroll 8
    for (int c = 0; c < C4_; ++c) a = fmaf(w[c], ss[c * 6 + j], a);
    if (half) P2[r] = a; else P1[r] = a;
  }
  __syncthreads();

  for (int q = t; q < C4_ * L_; q += 256) {
    int o = q / 6, i = q - o * 6;
    float sc = ge[o] * rsqrtf(ve[o] + EPS_);
    float p1i = P1[o * 6 + i], p2i = P2[o * 6 + i];
    float m = -INFINITY;
#pragma unroll
    for (int k = 0; k < 3; ++k) {
      int j = knn[i * 3 + k];
      float pre = P1[o * 6 + j] - p1i + p2i;          // W.[feat-xe ; xe]
      pre = (pre - me[o]) * sc + bee[o];
      pre = pre > 0.f ? pre : 0.2f * pre;             // leaky relu
      m = fmaxf(m, pre);
    }
    el[q] = m;
  }
  __syncthreads();

  // att: thread t == output channel oc
  {
    float acc[6];
    float bv = ba[t];
#pragma unroll
    for (int i = 0; i < 6; ++i) acc[i] = bv;
    for (int c = 0; c < C4_; ++c) {
      float w = wat[c * C_ + t];
#pragma unroll
      for (int i = 0; i < 6; ++i) acc[i] = fmaf(w, el[c * 6 + i], acc[i]);
    }
#pragma unroll
    for (int i = 0; i < 6; ++i)
      gate[((size_t)n * C_ + t) * L_ + i] = 1.f / (1.f + expf(-acc[i]));
  }
}

// ---------------- kernel 4: out[n,c,t,v] = sum_l x[n,c,l,t,v]*gate[n,c,l] ---
__global__ __launch_bounds__(256) void k_apply(const float* __restrict__ x,
                                               const float* __restrict__ gate,
                                               float* __restrict__ out) {
  const int F4 = T_ * V_ / 4;  // 400 float4 per (n,c)
  int tid = blockIdx.x * 256 + threadIdx.x;
  if (tid >= N_ * C_ * F4) return;
  int nc = tid / F4;
  int j = tid - nc * F4;
  const float4* xp = (const float4*)x + (size_t)nc * (L_ * F4) + j;
  const float* g = gate + (size_t)nc * L_;
  float4 a = make_float4(0.f, 0.f, 0.f, 0.f);
#pragma unroll
  for (int l = 0; l < L_; ++l) {
    float gl = g[l];
    float4 xv = xp[(size_t)l * F4];
    a.x = fmaf(xv.x, gl, a.x);
    a.y = fmaf(xv.y, gl, a.y);
    a.z = fmaf(xv.z, gl, a.z);
    a.w = fmaf(xv.w, gl, a.w);
  }
  ((float4*)out)[tid] = a;
}

extern "C" void kernel_launch(void* const* d_in, const int* in_sizes, int n_in,
                              void* d_out, int out_size, void* d_ws,
                              size_t ws_size, hipStream_t stream) {
  const float* x    = (const float*)d_in[0];
  const float* Wd   = (const float*)d_in[1];
  const float* bd   = (const float*)d_in[2];
  const float* gd   = (const float*)d_in[3];
  const float* bed  = (const float*)d_in[4];
  const float* md   = (const float*)d_in[5];
  const float* vd   = (const float*)d_in[6];
  const float* We   = (const float*)d_in[7];
  const float* ge   = (const float*)d_in[8];
  const float* bee  = (const float*)d_in[9];
  const float* me   = (const float*)d_in[10];
  const float* ve   = (const float*)d_in[11];
  const float* Wa   = (const float*)d_in[12];
  const float* ba   = (const float*)d_in[13];
  float* out = (float*)d_out;

  float* ws   = (float*)d_ws;
  float* xt   = ws;                                  // 1,228,800
  float* s    = xt + (size_t)N_ * C_ * L_ * V_;      // 12,288
  float* gate = s + (size_t)N_ * C4_ * L_;           // 49,152
  float* wtd  = gate + (size_t)N_ * C_ * L_;         // 16,384
  float* wat  = wtd + C_ * C4_;                      // 16,384

  k_wt<<<(2 * C_ * C4_ + 255) / 256, 256, 0, stream>>>(Wd, Wa, wtd, wat);

  const int total1 = N_ * C_ * L_ * V_;
  k_maxT<<<(total1 + 255) / 256, 256, 0, stream>>>(x, xt);

  k_down<<<N_ * L_, 128, 0, stream>>>(xt, wtd, bd, gd, bed, md, vd, s);

  k_edge<<<N_, 256, 0, stream>>>(s, We, ge, bee, me, ve, wat, ba, gate);

  const int total4 = N_ * C_ * (T_ * V_ / 4);
  k_apply<<<(total4 + 255) / 256, 256, 0, stream>>>(x, gate, out);
}

// Round 3
// 555.529 us; speedup vs baseline: 1.0398x; 1.0398x over previous
//
#include <hip/hip_runtime.h>
#include <hip/hip_bf16.h>
#include <math.h>

#define N_ 32
#define C_ 256
#define C4_ 64
#define L_ 6
#define T_ 64
#define V_ 25
#define VP 28          // padded V for float4 LDS tiles
#define EPS_ 1e-5f

// LAYERS flattened (joint indices per hierarchy level) + offsets
__device__ __constant__ int LIDX[45] = {
    1, 0, 20,
    0, 20, 12, 16, 2, 4, 8,
    12, 16, 2, 4, 8, 13, 17, 3, 5, 9,
    13, 17, 3, 5, 9, 14, 18, 6, 10,
    14, 18, 6, 10, 15, 19, 7, 11,
    15, 19, 7, 11, 21, 22, 23, 24};
__device__ __constant__ int LOFF[7] = {0, 3, 10, 20, 29, 37, 45};

// ---------------- kernel 0: transpose W_down and W_agg into workspace -------
__global__ __launch_bounds__(256) void k_wt(const float* __restrict__ Wd,
                                            const float* __restrict__ Wa,
                                            float* __restrict__ wtd,
                                            float* __restrict__ wat) {
  int tid = blockIdx.x * 256 + threadIdx.x;
  if (tid < C4_ * C_) {                 // W_down (64,256) -> [c][o]
    int o = tid / C_, c = tid - o * C_;
    wtd[c * C4_ + o] = Wd[tid];
  } else if (tid < 2 * C4_ * C_) {      // W_agg (256,64) -> [c][oc]
    int i = tid - C4_ * C_;
    int oc = i / C4_, c = i - oc * C4_;
    wat[c * C_ + oc] = Wa[i];
  }
}

// ---------------- kernel 1: max over T  (N,C,L,T,V) -> (N,C,L,V) ------------
// One block per (n,c). Fully float4-coalesced.
// Row [T=64][V=25] = 400 float4; float4 index slot+25k covers flat positions
// 100k + 4*slot + d  ->  (v,t-class) fixed per (slot,d):
//   v = (4*slot+d) % 25, cls = (4*slot+d)/25, t = 4k + cls.
// Thread (l,slot) max-reduces 16 float4 at stride 400B, scatters 4 partials
// into LDS [l][v*4+cls]; then 150 lanes b128-read + fmax -> coalesced store.
__global__ __launch_bounds__(192) void k_maxT(const float* __restrict__ x,
                                              float* __restrict__ xt) {
  __shared__ float red[L_ * 100];   // 2.4 KB
  int nc = blockIdx.x;
  int t = threadIdx.x;
  if (t < 150) {
    int l = t / 25, slot = t - l * 25;
    const float4* x4 = (const float4*)x + (size_t)nc * (L_ * 400) + l * 400 + slot;
    float4 m = x4[0];
#pragma unroll
    for (int k = 1; k < 16; ++k) {
      float4 v = x4[k * 25];
      m.x = fmaxf(m.x, v.x);
      m.y = fmaxf(m.y, v.y);
      m.z = fmaxf(m.z, v.z);
      m.w = fmaxf(m.w, v.w);
    }
    int p = 4 * slot;
    float mv[4] = {m.x, m.y, m.z, m.w};
#pragma unroll
    for (int d = 0; d < 4; ++d) {
      int fp = p + d;                 // 0..99
      int v = fp % 25, cls = fp / 25;
      red[l * 100 + v * 4 + cls] = mv[d];
    }
  }
  __syncthreads();
  if (t < 150) {
    float4 r = *(const float4*)&red[t * 4];   // t = l*25+v
    float m = fmaxf(fmaxf(r.x, r.y), fmaxf(r.z, r.w));
    xt[(size_t)nc * 150 + t] = m;             // layout [(n,c)][l*25+v] == [n,c,l,v]
  }
}

// ---------------- kernel 2: conv_down + BN + ReLU + joint-subset mean -------
// one block per (n,l); 128 threads; thread = (o_group 0..15) x (v_group 0..6)
__global__ __launch_bounds__(128) void k_down(
    const float* __restrict__ xt, const float* __restrict__ wtd,
    const float* __restrict__ bd, const float* __restrict__ gd,
    const float* __restrict__ bed, const float* __restrict__ md,
    const float* __restrict__ vd, float* __restrict__ s_out) {
  __shared__ float wls[64 * C4_];   // W chunk [c_local][o]  16 KB
  __shared__ float xs[64 * VP];     // x_t chunk [c_local][v] 7 KB
  __shared__ float hs[C4_ * VP];    // h [o][v]               7 KB

  int n = blockIdx.x / L_, l = blockIdx.x - n * L_;
  int t = threadIdx.x;
  int o0 = (t & 15) * 4;
  int vg = t >> 4;                  // 0..7
  bool active = vg < 7;
  int v0 = vg * 4;

  float acc[4][4] = {};

  for (int cc = 0; cc < C_; cc += 64) {
    __syncthreads();
    // stage W chunk (coalesced float4 from pre-transposed global)
    {
      const float4* src = (const float4*)(wtd + cc * C4_);
      float4* dst = (float4*)wls;
      for (int i = t; i < 64 * C4_ / 4; i += 128) dst[i] = src[i];
    }
    // stage x_t chunk with zero pad
    for (int i = t; i < 64 * VP; i += 128) {
      int c = i / VP, v = i - c * VP;
      xs[i] = (v < V_) ? xt[(((size_t)n * C_ + (cc + c)) * L_ + l) * V_ + v]
                       : 0.f;
    }
    __syncthreads();
    if (active) {
#pragma unroll 4
      for (int c = 0; c < 64; ++c) {
        float4 wv = *(const float4*)&wls[c * C4_ + o0];
        float4 xv = *(const float4*)&xs[c * VP + v0];
        acc[0][0] = fmaf(wv.x, xv.x, acc[0][0]);
        acc[0][1] = fmaf(wv.x, xv.y, acc[0][1]);
        acc[0][2] = fmaf(wv.x, xv.z, acc[0][2]);
        acc[0][3] = fmaf(wv.x, xv.w, acc[0][3]);
        acc[1][0] = fmaf(wv.y, xv.x, acc[1][0]);
        acc[1][1] = fmaf(wv.y, xv.y, acc[1][1]);
        acc[1][2] = fmaf(wv.y, xv.z, acc[1][2]);
        acc[1][3] = fmaf(wv.y, xv.w, acc[1][3]);
        acc[2][0] = fmaf(wv.z, xv.x, acc[2][0]);
        acc[2][1] = fmaf(wv.z, xv.y, acc[2][1]);
        acc[2][2] = fmaf(wv.z, xv.z, acc[2][2]);
        acc[2][3] = fmaf(wv.z, xv.w, acc[2][3]);
        acc[3][0] = fmaf(wv.w, xv.x, acc[3][0]);
        acc[3][1] = fmaf(wv.w, xv.y, acc[3][1]);
        acc[3][2] = fmaf(wv.w, xv.z, acc[3][2]);
        acc[3][3] = fmaf(wv.w, xv.w, acc[3][3]);
      }
    }
  }
  if (active) {
#pragma unroll
    for (int oj = 0; oj < 4; ++oj) {
      int o = o0 + oj;
      float sc = gd[o] * rsqrtf(vd[o] + EPS_);
      float base = bd[o] - md[o];
#pragma unroll
      for (int vj = 0; vj < 4; ++vj) {
        float hv = (acc[oj][vj] + base) * sc + bed[o];
        hs[o * VP + v0 + vj] = fmaxf(hv, 0.f);
      }
    }
  }
  __syncthreads();
  // joint-subset mean -> s[n][o][l]
  if (t < C4_) {
    float a = 0.f;
    int b0 = LOFF[l], b1 = LOFF[l + 1];
    for (int j = b0; j < b1; ++j) a += hs[t * VP + LIDX[j]];
    s_out[((size_t)n * C4_ + t) * L_ + l] = a / (float)(b1 - b0);
  }
}

// ---------------- kernel 3: EdgeConv + aggregate + sigmoid gate -------------
// one block per n; 256 threads
__global__ __launch_bounds__(256) void k_edge(
    const float* __restrict__ s_in, const float* __restrict__ We,
    const float* __restrict__ ge, const float* __restrict__ bee,
    const float* __restrict__ me, const float* __restrict__ ve,
    const float* __restrict__ wat, const float* __restrict__ ba,
    float* __restrict__ gate) {
  __shared__ float ss[C4_ * L_];     // s [c][i]
  __shared__ float P1[C4_ * L_];     // dot(W_edge[:, :64][o], s[:,j])
  __shared__ float P2[C4_ * L_];     // dot(W_edge[:, 64:][o], s[:,j])
  __shared__ float dist[L_ * L_];
  __shared__ int knn[L_ * 3];
  __shared__ float el[C4_ * L_];     // e after max over k, [c][i]

  int n = blockIdx.x;
  int t = threadIdx.x;
  for (int q = t; q < C4_ * L_; q += 256)
    ss[q] = s_in[(size_t)n * (C4_ * L_) + q];
  __syncthreads();

  if (t < 36) {
    int i = t / 6, j = t - (t / 6) * 6;
    float d = 0.f;
    for (int c = 0; c < C4_; ++c) {
      float df = ss[c * 6 + i] - ss[c * 6 + j];
      d = fmaf(df, df, d);
    }
    dist[t] = -d;   // exact 0 on diagonal, negative elsewhere
  }
  __syncthreads();
  if (t < 6) {
    unsigned used = 0;
    for (int k = 0; k < 3; ++k) {
      float best = -INFINITY;
      int bj = 0;
      for (int j = 0; j < 6; ++j) {
        if (!((used >> j) & 1u) && dist[t * 6 + j] > best) {
          best = dist[t * 6 + j];
          bj = j;
        }
      }
      used |= 1u << bj;
      knn[t * 3 + k] = bj;
    }
  }
  __syncthreads();

  for (int q = t; q < 2 * C4_ * L_; q += 256) {
    int half = q / (C4_ * L_);
    int r = q - half * (C4_ * L_);
    int o = r / 6, j = r - o * 6;
    const float* w = We + o * 128 + half * 64;
    float a = 0.f;
#pragma unroll 8
    for (int c = 0; c < C4_; ++c) a = fmaf(w[c], ss[c * 6 + j], a);
    if (half) P2[r] = a; else P1[r] = a;
  }
  __syncthreads();

  for (int q = t; q < C4_ * L_; q += 256) {
    int o = q / 6, i = q - o * 6;
    float sc = ge[o] * rsqrtf(ve[o] + EPS_);
    float p1i = P1[o * 6 + i], p2i = P2[o * 6 + i];
    float m = -INFINITY;
#pragma unroll
    for (int k = 0; k < 3; ++k) {
      int j = knn[i * 3 + k];
      float pre = P1[o * 6 + j] - p1i + p2i;          // W.[feat-xe ; xe]
      pre = (pre - me[o]) * sc + bee[o];
      pre = pre > 0.f ? pre : 0.2f * pre;             // leaky relu
      m = fmaxf(m, pre);
    }
    el[q] = m;
  }
  __syncthreads();

  // att: thread t == output channel oc
  {
    float acc[6];
    float bv = ba[t];
#pragma unroll
    for (int i = 0; i < 6; ++i) acc[i] = bv;
    for (int c = 0; c < C4_; ++c) {
      float w = wat[c * C_ + t];
#pragma unroll
      for (int i = 0; i < 6; ++i) acc[i] = fmaf(w, el[c * 6 + i], acc[i]);
    }
#pragma unroll
    for (int i = 0; i < 6; ++i)
      gate[((size_t)n * C_ + t) * L_ + i] = 1.f / (1.f + expf(-acc[i]));
  }
}

// ---------------- kernel 4: out[n,c,t,v] = sum_l x[n,c,l,t,v]*gate[n,c,l] ---
__global__ __launch_bounds__(256) void k_apply(const float* __restrict__ x,
                                               const float* __restrict__ gate,
                                               float* __restrict__ out) {
  const int F4 = T_ * V_ / 4;  // 400 float4 per (n,c)
  int tid = blockIdx.x * 256 + threadIdx.x;
  if (tid >= N_ * C_ * F4) return;
  int nc = tid / F4;
  int j = tid - nc * F4;
  const float4* xp = (const float4*)x + (size_t)nc * (L_ * F4) + j;
  const float* g = gate + (size_t)nc * L_;
  float4 a = make_float4(0.f, 0.f, 0.f, 0.f);
#pragma unroll
  for (int l = 0; l < L_; ++l) {
    float gl = g[l];
    float4 xv = xp[(size_t)l * F4];
    a.x = fmaf(xv.x, gl, a.x);
    a.y = fmaf(xv.y, gl, a.y);
    a.z = fmaf(xv.z, gl, a.z);
    a.w = fmaf(xv.w, gl, a.w);
  }
  ((float4*)out)[tid] = a;
}

extern "C" void kernel_launch(void* const* d_in, const int* in_sizes, int n_in,
                              void* d_out, int out_size, void* d_ws,
                              size_t ws_size, hipStream_t stream) {
  const float* x    = (const float*)d_in[0];
  const float* Wd   = (const float*)d_in[1];
  const float* bd   = (const float*)d_in[2];
  const float* gd   = (const float*)d_in[3];
  const float* bed  = (const float*)d_in[4];
  const float* md   = (const float*)d_in[5];
  const float* vd   = (const float*)d_in[6];
  const float* We   = (const float*)d_in[7];
  const float* ge   = (const float*)d_in[8];
  const float* bee  = (const float*)d_in[9];
  const float* me   = (const float*)d_in[10];
  const float* ve   = (const float*)d_in[11];
  const float* Wa   = (const float*)d_in[12];
  const float* ba   = (const float*)d_in[13];
  float* out = (float*)d_out;

  float* ws   = (float*)d_ws;
  float* xt   = ws;                                  // 1,228,800
  float* s    = xt + (size_t)N_ * C_ * L_ * V_;      // 12,288
  float* gate = s + (size_t)N_ * C4_ * L_;           // 49,152
  float* wtd  = gate + (size_t)N_ * C_ * L_;         // 16,384
  float* wat  = wtd + C_ * C4_;                      // 16,384

  k_wt<<<(2 * C_ * C4_ + 255) / 256, 256, 0, stream>>>(Wd, Wa, wtd, wat);

  k_maxT<<<N_ * C_, 192, 0, stream>>>(x, xt);

  k_down<<<N_ * L_, 128, 0, stream>>>(xt, wtd, bd, gd, bed, md, vd, s);

  k_edge<<<N_, 256, 0, stream>>>(s, We, ge, bee, me, ve, wat, ba, gate);

  const int total4 = N_ * C_ * (T_ * V_ / 4);
  k_apply<<<(total4 + 255) / 256, 256, 0, stream>>>(x, gate, out);
}

// Round 4
// 552.127 us; speedup vs baseline: 1.0462x; 1.0062x over previous
//
#include <hip/hip_runtime.h>
#include <hip/hip_bf16.h>
#include <math.h>

#define N_ 32
#define C_ 256
#define C4_ 64
#define L_ 6
#define T_ 64
#define V_ 25
#define VP 28          // padded V for float4 LDS tiles
#define EPS_ 1e-5f

#define NPANEL (N_ * C_ * L_)        // 49152 panels of [T][V]
#define PPB 10                       // panels per block in k_maxT
#define MAXT_BLOCKS ((NPANEL + PPB - 1) / PPB)   // 4916
#define WT_BLOCKS (2 * C_ * C4_ / 256)           // 128 transpose blocks

// LAYERS flattened (joint indices per hierarchy level) + offsets
__device__ __constant__ int LIDX[45] = {
    1, 0, 20,
    0, 20, 12, 16, 2, 4, 8,
    12, 16, 2, 4, 8, 13, 17, 3, 5, 9,
    13, 17, 3, 5, 9, 14, 18, 6, 10,
    14, 18, 6, 10, 15, 19, 7, 11,
    15, 19, 7, 11, 21, 22, 23, 24};
__device__ __constant__ int LOFF[7] = {0, 3, 10, 20, 29, 37, 45};

// ---------------- kernel 1: max over T (fused with weight transposes) -------
// Blocks [0, MAXT_BLOCKS): 10 panels each, 25 threads/panel (250/256 lanes).
// Panel p=(n,c,l) is [T=64][V=25] = 400 float4 = 16 deep x 25 slots; float4
// slot+25k covers flat 100k+4*slot+d -> fixed (v=fp%25, cls=fp/25), t=4k+cls.
// Blocks [MAXT_BLOCKS, +WT_BLOCKS): transpose W_down / W_agg into workspace.
__global__ __launch_bounds__(256) void k_maxT(const float* __restrict__ x,
                                              float* __restrict__ xt,
                                              const float* __restrict__ Wd,
                                              const float* __restrict__ Wa,
                                              float* __restrict__ wtd,
                                              float* __restrict__ wat) {
  int t = threadIdx.x;
  if (blockIdx.x >= MAXT_BLOCKS) {   // weight-transpose tail blocks
    int tid = (blockIdx.x - MAXT_BLOCKS) * 256 + t;
    if (tid < C4_ * C_) {            // W_down (64,256) -> [c][o]
      int o = tid / C_, c = tid - o * C_;
      wtd[c * C4_ + o] = Wd[tid];
    } else {                         // W_agg (256,64) -> [c][oc]
      int i = tid - C4_ * C_;
      int oc = i / C4_, c = i - oc * C4_;
      wat[c * C_ + oc] = Wa[i];
    }
    return;
  }
  __shared__ float red[PPB * 100];   // 4 KB
  int lp = t / 25, slot = t - lp * 25;
  int p = blockIdx.x * PPB + lp;
  bool act = (t < PPB * 25) && (p < NPANEL);
  if (act) {
    const float4* x4 = (const float4*)x + (size_t)p * 400 + slot;
    float4 m = x4[0];
#pragma unroll
    for (int k = 1; k < 16; ++k) {
      float4 v = x4[k * 25];
      m.x = fmaxf(m.x, v.x);
      m.y = fmaxf(m.y, v.y);
      m.z = fmaxf(m.z, v.z);
      m.w = fmaxf(m.w, v.w);
    }
    float mv[4] = {m.x, m.y, m.z, m.w};
#pragma unroll
    for (int d = 0; d < 4; ++d) {
      int fp = 4 * slot + d;         // 0..99
      int v = fp % 25, cls = fp / 25;
      red[lp * 100 + v * 4 + cls] = mv[d];
    }
  }
  __syncthreads();
  if (act) {
    float4 r = *(const float4*)&red[lp * 100 + slot * 4];
    float m = fmaxf(fmaxf(r.x, r.y), fmaxf(r.z, r.w));
    xt[(size_t)p * 25 + slot] = m;   // [(n,c,l)][v] layout
  }
}

// ---------------- kernel 2: conv_down + BN + ReLU + joint-subset mean -------
// one block per (n,l); 128 threads; thread = (o_group 0..15) x (v_group 0..6)
__global__ __launch_bounds__(128) void k_down(
    const float* __restrict__ xt, const float* __restrict__ wtd,
    const float* __restrict__ bd, const float* __restrict__ gd,
    const float* __restrict__ bed, const float* __restrict__ md,
    const float* __restrict__ vd, float* __restrict__ s_out) {
  __shared__ float wls[64 * C4_];   // W chunk [c_local][o]  16 KB
  __shared__ float xs[64 * VP];     // x_t chunk [c_local][v] 7 KB
  __shared__ float hs[C4_ * VP];    // h [o][v]               7 KB

  int n = blockIdx.x / L_, l = blockIdx.x - n * L_;
  int t = threadIdx.x;
  int o0 = (t & 15) * 4;
  int vg = t >> 4;                  // 0..7
  bool active = vg < 7;
  int v0 = vg * 4;

  float acc[4][4] = {};

  for (int cc = 0; cc < C_; cc += 64) {
    __syncthreads();
    {
      const float4* src = (const float4*)(wtd + cc * C4_);
      float4* dst = (float4*)wls;
      for (int i = t; i < 64 * C4_ / 4; i += 128) dst[i] = src[i];
    }
    for (int i = t; i < 64 * VP; i += 128) {
      int c = i / VP, v = i - c * VP;
      xs[i] = (v < V_) ? xt[(((size_t)n * C_ + (cc + c)) * L_ + l) * V_ + v]
                       : 0.f;
    }
    __syncthreads();
    if (active) {
#pragma unroll 4
      for (int c = 0; c < 64; ++c) {
        float4 wv = *(const float4*)&wls[c * C4_ + o0];
        float4 xv = *(const float4*)&xs[c * VP + v0];
        acc[0][0] = fmaf(wv.x, xv.x, acc[0][0]);
        acc[0][1] = fmaf(wv.x, xv.y, acc[0][1]);
        acc[0][2] = fmaf(wv.x, xv.z, acc[0][2]);
        acc[0][3] = fmaf(wv.x, xv.w, acc[0][3]);
        acc[1][0] = fmaf(wv.y, xv.x, acc[1][0]);
        acc[1][1] = fmaf(wv.y, xv.y, acc[1][1]);
        acc[1][2] = fmaf(wv.y, xv.z, acc[1][2]);
        acc[1][3] = fmaf(wv.y, xv.w, acc[1][3]);
        acc[2][0] = fmaf(wv.z, xv.x, acc[2][0]);
        acc[2][1] = fmaf(wv.z, xv.y, acc[2][1]);
        acc[2][2] = fmaf(wv.z, xv.z, acc[2][2]);
        acc[2][3] = fmaf(wv.z, xv.w, acc[2][3]);
        acc[3][0] = fmaf(wv.w, xv.x, acc[3][0]);
        acc[3][1] = fmaf(wv.w, xv.y, acc[3][1]);
        acc[3][2] = fmaf(wv.w, xv.z, acc[3][2]);
        acc[3][3] = fmaf(wv.w, xv.w, acc[3][3]);
      }
    }
  }
  if (active) {
#pragma unroll
    for (int oj = 0; oj < 4; ++oj) {
      int o = o0 + oj;
      float sc = gd[o] * rsqrtf(vd[o] + EPS_);
      float base = bd[o] - md[o];
#pragma unroll
      for (int vj = 0; vj < 4; ++vj) {
        float hv = (acc[oj][vj] + base) * sc + bed[o];
        hs[o * VP + v0 + vj] = fmaxf(hv, 0.f);
      }
    }
  }
  __syncthreads();
  if (t < C4_) {
    float a = 0.f;
    int b0 = LOFF[l], b1 = LOFF[l + 1];
    for (int j = b0; j < b1; ++j) a += hs[t * VP + LIDX[j]];
    s_out[((size_t)n * C4_ + t) * L_ + l] = a / (float)(b1 - b0);
  }
}

// ---------------- kernel 3: EdgeConv + aggregate + sigmoid gate -------------
// one block per n; 256 threads
__global__ __launch_bounds__(256) void k_edge(
    const float* __restrict__ s_in, const float* __restrict__ We,
    const float* __restrict__ ge, const float* __restrict__ bee,
    const float* __restrict__ me, const float* __restrict__ ve,
    const float* __restrict__ wat, const float* __restrict__ ba,
    float* __restrict__ gate) {
  __shared__ float ss[C4_ * L_];     // s [c][i]
  __shared__ float P1[C4_ * L_];
  __shared__ float P2[C4_ * L_];
  __shared__ float dist[L_ * L_];
  __shared__ int knn[L_ * 3];
  __shared__ float el[C4_ * L_];

  int n = blockIdx.x;
  int t = threadIdx.x;
  for (int q = t; q < C4_ * L_; q += 256)
    ss[q] = s_in[(size_t)n * (C4_ * L_) + q];
  __syncthreads();

  if (t < 36) {
    int i = t / 6, j = t - (t / 6) * 6;
    float d = 0.f;
    for (int c = 0; c < C4_; ++c) {
      float df = ss[c * 6 + i] - ss[c * 6 + j];
      d = fmaf(df, df, d);
    }
    dist[t] = -d;   // exact 0 on diagonal
  }
  __syncthreads();
  if (t < 6) {
    unsigned used = 0;
    for (int k = 0; k < 3; ++k) {
      float best = -INFINITY;
      int bj = 0;
      for (int j = 0; j < 6; ++j) {
        if (!((used >> j) & 1u) && dist[t * 6 + j] > best) {
          best = dist[t * 6 + j];
          bj = j;
        }
      }
      used |= 1u << bj;
      knn[t * 3 + k] = bj;
    }
  }
  __syncthreads();

  for (int q = t; q < 2 * C4_ * L_; q += 256) {
    int half = q / (C4_ * L_);
    int r = q - half * (C4_ * L_);
    int o = r / 6, j = r - o * 6;
    const float* w = We + o * 128 + half * 64;
    float a = 0.f;
#pragma unroll 8
    for (int c = 0; c < C4_; ++c) a = fmaf(w[c], ss[c * 6 + j], a);
    if (half) P2[r] = a; else P1[r] = a;
  }
  __syncthreads();

  for (int q = t; q < C4_ * L_; q += 256) {
    int o = q / 6, i = q - o * 6;
    float sc = ge[o] * rsqrtf(ve[o] + EPS_);
    float p1i = P1[o * 6 + i], p2i = P2[o * 6 + i];
    float m = -INFINITY;
#pragma unroll
    for (int k = 0; k < 3; ++k) {
      int j = knn[i * 3 + k];
      float pre = P1[o * 6 + j] - p1i + p2i;
      pre = (pre - me[o]) * sc + bee[o];
      pre = pre > 0.f ? pre : 0.2f * pre;
      m = fmaxf(m, pre);
    }
    el[q] = m;
  }
  __syncthreads();

  {
    float acc[6];
    float bv = ba[t];
#pragma unroll
    for (int i = 0; i < 6; ++i) acc[i] = bv;
    for (int c = 0; c < C4_; ++c) {
      float w = wat[c * C_ + t];
#pragma unroll
      for (int i = 0; i < 6; ++i) acc[i] = fmaf(w, el[c * 6 + i], acc[i]);
    }
#pragma unroll
    for (int i = 0; i < 6; ++i)
      gate[((size_t)n * C_ + t) * L_ + i] = 1.f / (1.f + expf(-acc[i]));
  }
}

// ---------------- kernel 4: out[n,c,t,v] = sum_l x[n,c,l,t,v]*gate[n,c,l] ---
__global__ __launch_bounds__(256) void k_apply(const float* __restrict__ x,
                                               const float* __restrict__ gate,
                                               float* __restrict__ out) {
  const int F4 = T_ * V_ / 4;  // 400 float4 per (n,c,l)
  int tid = blockIdx.x * 256 + threadIdx.x;
  if (tid >= N_ * C_ * F4) return;
  int nc = tid / F4;
  int j = tid - nc * F4;
  const float4* xp = (const float4*)x + (size_t)nc * (L_ * F4) + j;
  const float* g = gate + (size_t)nc * L_;
  float4 a = make_float4(0.f, 0.f, 0.f, 0.f);
#pragma unroll
  for (int l = 0; l < L_; ++l) {
    float gl = g[l];
    float4 xv = xp[(size_t)l * F4];
    a.x = fmaf(xv.x, gl, a.x);
    a.y = fmaf(xv.y, gl, a.y);
    a.z = fmaf(xv.z, gl, a.z);
    a.w = fmaf(xv.w, gl, a.w);
  }
  ((float4*)out)[tid] = a;
}

extern "C" void kernel_launch(void* const* d_in, const int* in_sizes, int n_in,
                              void* d_out, int out_size, void* d_ws,
                              size_t ws_size, hipStream_t stream) {
  const float* x    = (const float*)d_in[0];
  const float* Wd   = (const float*)d_in[1];
  const float* bd   = (const float*)d_in[2];
  const float* gd   = (const float*)d_in[3];
  const float* bed  = (const float*)d_in[4];
  const float* md   = (const float*)d_in[5];
  const float* vd   = (const float*)d_in[6];
  const float* We   = (const float*)d_in[7];
  const float* ge   = (const float*)d_in[8];
  const float* bee  = (const float*)d_in[9];
  const float* me   = (const float*)d_in[10];
  const float* ve   = (const float*)d_in[11];
  const float* Wa   = (const float*)d_in[12];
  const float* ba   = (const float*)d_in[13];
  float* out = (float*)d_out;

  float* ws   = (float*)d_ws;
  float* xt   = ws;                                  // 1,228,800
  float* s    = xt + (size_t)N_ * C_ * L_ * V_;      // 12,288
  float* gate = s + (size_t)N_ * C4_ * L_;           // 49,152
  float* wtd  = gate + (size_t)N_ * C_ * L_;         // 16,384
  float* wat  = wtd + C_ * C4_;                      // 16,384

  k_maxT<<<MAXT_BLOCKS + WT_BLOCKS, 256, 0, stream>>>(x, xt, Wd, Wa, wtd, wat);

  k_down<<<N_ * L_, 128, 0, stream>>>(xt, wtd, bd, gd, bed, md, vd, s);

  k_edge<<<N_, 256, 0, stream>>>(s, We, ge, bee, me, ve, wat, ba, gate);

  const int total4 = N_ * C_ * (T_ * V_ / 4);
  k_apply<<<(total4 + 255) / 256, 256, 0, stream>>>(x, gate, out);
}